// Round 7
// baseline (1068.457 us; speedup 1.0000x reference)
//
#include <hip/hip_runtime.h>
#include <stdint.h>

typedef int v4i __attribute__((ext_vector_type(4)));

#define M_DIM 8192   // B*S = 2*4096
#define N_DIM 8192   // OUT
#define K_DIM 2048   // IN
#define RISKY_TAU 1e-4f
#define BUCKET_CAP 1024
#define SLOT 16384   // LDS buffer: A[128][64] 8KB + B[128][64] 8KB

// async global->LDS, 16B per lane (dest = wave-uniform base + lane*16)
#define ASYNC16(g, l) __builtin_amdgcn_global_load_lds(                        \
    (const __attribute__((address_space(1))) void*)(uintptr_t)(g),             \
    (__attribute__((address_space(3))) void*)(uint32_t)(uintptr_t)(l), 16, 0, 0)

// ---------------- 1) numpy-pairwise f32 sum of |w| ----------------
__global__ __launch_bounds__(256) void abssum_stage1(const float* __restrict__ w,
                                                     float* __restrict__ s1) {
  int b = blockIdx.x * 256 + threadIdx.x;  // 131072 leaf blocks of 128
  const float* p = w + (size_t)b * 128;
  float r[8];
#pragma unroll
  for (int j = 0; j < 8; j++) r[j] = fabsf(p[j]);
  for (int i = 8; i < 128; i += 8) {
#pragma unroll
    for (int j = 0; j < 8; j++) r[j] += fabsf(p[i + j]);
  }
  s1[b] = ((r[0] + r[1]) + (r[2] + r[3])) + ((r[4] + r[5]) + (r[6] + r[7]));
}

__global__ __launch_bounds__(256) void abssum_stage2(const float* __restrict__ s1,
                                                     float* __restrict__ s2) {
  int t = blockIdx.x * 256 + threadIdx.x;  // 4096 threads
  float v[32];
#pragma unroll
  for (int i = 0; i < 32; i++) v[i] = s1[t * 32 + i];
#pragma unroll
  for (int s = 1; s < 32; s *= 2) {
#pragma unroll
    for (int i = 0; i < 32; i += 2 * s) v[i] += v[i + s];
  }
  s2[t] = v[0];
}

__global__ __launch_bounds__(256) void gamma_stage3(const float* __restrict__ s2,
                                                    float* __restrict__ gp) {
  int t = threadIdx.x;  // 256 threads, one block
  float v[16];
#pragma unroll
  for (int i = 0; i < 16; i++) v[i] = s2[t * 16 + i];
#pragma unroll
  for (int s = 1; s < 16; s *= 2) {
#pragma unroll
    for (int i = 0; i < 16; i += 2 * s) v[i] += v[i + s];
  }
  __shared__ float sm[256];
  sm[t] = v[0];
  for (int s = 1; s < 256; s *= 2) {
    __syncthreads();
    if ((t & (2 * s - 1)) == 0) sm[t] += sm[t + s];
  }
  __syncthreads();
  if (t == 0) {
    float g = sm[0] * 0x1p-24f;  // /(8192*2048), exact pow2 scale
    gp[0] = fmaxf(g, 1e-5f);
  }
}

__global__ void zero_counts(int* __restrict__ counts) {
  counts[threadIdx.x] = 0;
}

// ---------------- 2) ternary weight quant + risky-midpoint detection ----------------
__global__ __launch_bounds__(256) void wq_kernel(const float4* __restrict__ w4,
                                                 const float* __restrict__ gp,
                                                 int* __restrict__ wq,
                                                 int* __restrict__ counts,
                                                 int* __restrict__ buckets) {
  int i = blockIdx.x * 256 + threadIdx.x;
  float g = gp[0];
  float4 v = w4[i];
  float e[4] = {v.x, v.y, v.z, v.w};
  int q[4];
#pragma unroll
  for (int c = 0; c < 4; c++) {
    q[c] = (int)rintf(fminf(fmaxf(e[c] / g, -1.0f), 1.0f));
    float t = fabsf(e[c]) / g;
    if (fabsf(t - 0.5f) < RISKY_TAU) {
      int flat = i * 4 + c;
      int n = flat >> 11;          // weight row (output col)
      int k = flat & 2047;
      int sgn_neg = (e[c] < 0.0f) ? 1 : 0;
      int sbit = (q[c] == 0) ? sgn_neg : (1 - sgn_neg);
      int b = n >> 7;
      int idx = atomicAdd(&counts[b], 1);
      if (idx < BUCKET_CAP)
        buckets[b * BUCKET_CAP + idx] = k | (n << 11) | (sbit << 24);
    }
  }
  wq[i] = (q[0] & 0xFF) | ((q[1] & 0xFF) << 8) | ((q[2] & 0xFF) << 16) | ((q[3] & 0xFF) << 24);
}

// ---------------- 3) fused LayerNorm + absmax int8 quant (one block per row) ----------------
__global__ __launch_bounds__(256) void lnq_kernel(const float* __restrict__ x,
                                                  const float* __restrict__ gp,
                                                  int8_t* __restrict__ xq,
                                                  float* __restrict__ scales) {
  const int row = blockIdx.x;
  const int t = threadIdx.x;
  const float4* xr = (const float4*)(x + (size_t)row * K_DIM);
  float4 a = xr[t];
  float4 b = xr[t + 256];
  double v[8] = {a.x, a.y, a.z, a.w, b.x, b.y, b.z, b.w};
  double s = 0.0, ss = 0.0;
#pragma unroll
  for (int i = 0; i < 8; i++) { s += v[i]; ss += v[i] * v[i]; }
  __shared__ double sm1[256], sm2[256];
  sm1[t] = s; sm2[t] = ss;
  __syncthreads();
  for (int off = 128; off > 0; off >>= 1) {
    if (t < off) { sm1[t] += sm1[t + off]; sm2[t] += sm2[t + off]; }
    __syncthreads();
  }
  double mu = sm1[0] * (1.0 / 2048.0);
  double var = sm2[0] * (1.0 / 2048.0) - mu * mu;  // biased variance
  double inv = 1.0 / sqrt(var + 1e-5);
  __syncthreads();
  double mx = 0.0;
#pragma unroll
  for (int i = 0; i < 8; i++) {
    v[i] = (v[i] - mu) * inv;
    double av = fabs(v[i]);
    if (av > mx) mx = av;
  }
  sm1[t] = mx;
  __syncthreads();
  for (int off = 128; off > 0; off >>= 1) {
    if (t < off) sm1[t] = fmax(sm1[t], sm1[t + off]);
    __syncthreads();
  }
  double eta = fmax(sm1[0], 1e-5);
  double r = 127.0 / eta;
  int q[8];
#pragma unroll
  for (int i = 0; i < 8; i++) {
    double qq = rint(v[i] * r);  // round-half-even, then clip
    qq = fmin(fmax(qq, -128.0), 127.0);
    q[i] = (int)qq;
  }
  int p0 = (q[0] & 0xFF) | ((q[1] & 0xFF) << 8) | ((q[2] & 0xFF) << 16) | ((q[3] & 0xFF) << 24);
  int p1 = (q[4] & 0xFF) | ((q[5] & 0xFF) << 8) | ((q[6] & 0xFF) << 16) | ((q[7] & 0xFF) << 24);
  int* orow = (int*)(xq + (size_t)row * K_DIM);
  orow[t] = p0;
  orow[t + 256] = p1;
  if (t == 0) scales[row] = (float)((double)gp[0] * eta * (1.0 / 127.0));
}

// ---------------- 4) int8 MFMA GEMM: 128x128 tile, 2-phase double-buffer ----------------
// Minimum-2-phase pipeline (guide T3 recipe): stage tile t+1 into buf^1 BEFORE computing
// tile t from buf; ONE __syncthreads (vmcnt0+lgkmcnt0 drain) per K-step. At most one tile
// (4 loads/wave) in flight -> L2 residency like round-4, latency hidden under compute.
__global__ __launch_bounds__(256, 4) void gemm_i8_kernel(const int8_t* __restrict__ A,
                                                         const int8_t* __restrict__ B,
                                                         const float* __restrict__ scales,
                                                         const float* __restrict__ bias,
                                                         const int* __restrict__ counts,
                                                         const int* __restrict__ buckets,
                                                         float* __restrict__ C) {
  __shared__ alignas(16) int8_t lds[2 * SLOT];  // 32 KiB -> 4 blocks/CU
  const int tid = threadIdx.x;
  const int wave = tid >> 6;
  const int lane = tid & 63;
  const int brow = blockIdx.y * 128;
  const int bcol = blockIdx.x * 128;

  // staging: 8 chunks of 1024B per matrix per tile; wave handles chunks {2w, 2w+1}.
  const int rA0 = (wave * 2 + 0) * 16 + (lane >> 2);
  const int rA1 = (wave * 2 + 1) * 16 + (lane >> 2);
  const int c16 = lane & 3;
  const int cA0 = ((c16 ^ ((rA0 >> 1) & 3)) << 4);
  const int cA1 = ((c16 ^ ((rA1 >> 1) & 3)) << 4);
  const int8_t* gA0 = A + (size_t)(brow + rA0) * K_DIM + cA0;
  const int8_t* gA1 = A + (size_t)(brow + rA1) * K_DIM + cA1;
  const int8_t* gB0 = B + (size_t)(bcol + rA0) * K_DIM + cA0;
  const int8_t* gB1 = B + (size_t)(bcol + rA1) * K_DIM + cA1;
  const int dA0 = (wave * 2 + 0) * 1024;          // buffer-relative LDS dests (wave-uniform)
  const int dA1 = (wave * 2 + 1) * 1024;
  const int dB0 = 8192 + (wave * 2 + 0) * 1024;
  const int dB1 = 8192 + (wave * 2 + 1) * 1024;

  // fragment read offsets (swizzled), buffer-relative
  const int wr = wave >> 1, wc = wave & 1;
  int aoff[4], boff[4];
#pragma unroll
  for (int i = 0; i < 4; i++) {
    int lr = wr * 64 + i * 16 + (lane & 15);
    aoff[i] = lr * 64 + ((((lane >> 4) ^ ((lr >> 1) & 3))) << 4);
    int lc = wc * 64 + i * 16 + (lane & 15);
    boff[i] = 8192 + lc * 64 + ((((lane >> 4) ^ ((lc >> 1) & 3))) << 4);
  }

  v4i acc[4][4];
  const v4i vzero = {0, 0, 0, 0};
#pragma unroll
  for (int i = 0; i < 4; i++)
#pragma unroll
    for (int j = 0; j < 4; j++) acc[i][j] = vzero;

  // prologue: stage tile 0 -> buf 0; drain
  ASYNC16(gA0, lds + dA0);
  ASYNC16(gA1, lds + dA1);
  ASYNC16(gB0, lds + dB0);
  ASYNC16(gB1, lds + dB1);
  __syncthreads();  // vmcnt(0): tile 0 landed

  int cur = 0;
  for (int t = 0; t < 32; ++t) {
    // issue next-tile staging first (hides under this tile's ds_read+MFMA)
    if (t < 31) {
      const int kt = (t + 1) * 64;
      const int sb = (cur ^ 1) * SLOT;
      ASYNC16(gA0 + kt, lds + sb + dA0);
      ASYNC16(gA1 + kt, lds + sb + dA1);
      ASYNC16(gB0 + kt, lds + sb + dB0);
      ASYNC16(gB1 + kt, lds + sb + dB1);
    }
    const int rb = cur * SLOT;
    v4i af[4], bf[4];
#pragma unroll
    for (int i = 0; i < 4; i++) af[i] = *(const v4i*)(lds + rb + aoff[i]);
#pragma unroll
    for (int j = 0; j < 4; j++) bf[j] = *(const v4i*)(lds + rb + boff[j]);
    __builtin_amdgcn_s_setprio(1);
#pragma unroll
    for (int i = 0; i < 4; i++)
#pragma unroll
      for (int j = 0; j < 4; j++)
        acc[i][j] = __builtin_amdgcn_mfma_i32_16x16x64_i8(af[i], bf[j], acc[i][j], 0, 0, 0);
    __builtin_amdgcn_s_setprio(0);
    __syncthreads();  // one drain per K-step: tile t+1 landed; ds_reads of buf done
    cur ^= 1;
  }

  // double accumulators (midpoint = odd integer), then apply risky corrections
#pragma unroll
  for (int i = 0; i < 4; i++)
#pragma unroll
    for (int j = 0; j < 4; j++) acc[i][j] = acc[i][j] + acc[i][j];

  const int crow0 = brow + wr * 64;
  const int ccol0 = bcol + wc * 64;

#define CORR(J)                                                                \
  {                                                                            \
    _Pragma("unroll") for (int i = 0; i < 4; i++) {                            \
      _Pragma("unroll") for (int r = 0; r < 4; r++) {                          \
        int grow = crow0 + i * 16 + ((lane >> 4) << 2) + r;                    \
        int xv = (int)A[(size_t)grow * K_DIM + k];                             \
        acc[i][J][r] += sv * xv;                                               \
      }                                                                        \
    }                                                                          \
  }

  {
    int bkt = bcol >> 7;
    int cnt = counts[bkt];
    if (cnt > BUCKET_CAP) cnt = BUCKET_CAP;
    const int* bk = buckets + bkt * BUCKET_CAP;
    for (int e = 0; e < cnt; ++e) {
      int word = bk[e];
      int k = word & 2047;
      int n = (word >> 11) & 8191;
      int sv = ((word >> 24) & 1) ? -1 : 1;
      int lc = n - bcol;  // in [0,128)
      if (((lc >> 6) & 1) == wc && (lc & 15) == (lane & 15)) {
        int j = (lc >> 4) & 3;
        switch (j) {
          case 0: CORR(0); break;
          case 1: CORR(1); break;
          case 2: CORR(2); break;
          case 3: CORR(3); break;
        }
      }
    }
  }
#undef CORR

  // epilogue: C[m][n] = (2*acc_corrected) * (scale_m/2) + bias[n]; nontemporal stores
#pragma unroll
  for (int i = 0; i < 4; i++) {
#pragma unroll
    for (int r = 0; r < 4; r++) {
      int grow = crow0 + i * 16 + ((lane >> 4) << 2) + r;
      float sc = scales[grow] * 0.5f;
      float* crow = C + (size_t)grow * N_DIM;
#pragma unroll
      for (int j = 0; j < 4; j++) {
        int gcol = ccol0 + j * 16 + (lane & 15);
        __builtin_nontemporal_store((float)acc[i][j][r] * sc + bias[gcol], &crow[gcol]);
      }
    }
  }
}

extern "C" void kernel_launch(void* const* d_in, const int* in_sizes, int n_in,
                              void* d_out, int out_size, void* d_ws, size_t ws_size,
                              hipStream_t stream) {
  const float* x = (const float*)d_in[0];
  const float* w = (const float*)d_in[1];
  const float* bias = (const float*)d_in[2];
  float* out = (float*)d_out;

  char* ws = (char*)d_ws;
  float* s1 = (float*)(ws);                          // 512 KiB
  float* s2 = (float*)(ws + 0x100000);               // 16 KiB
  float* gamma_f = (float*)(ws + 0x110000);          // 4 B
  float* scales = (float*)(ws + 0x120000);           // 32 KiB
  int* counts = (int*)(ws + 0x130000);               // 64 * 4 B
  int* buckets = (int*)(ws + 0x131000);              // 256 KiB
  int8_t* Aq = (int8_t*)(ws + 0x200000);                             // 16 MiB
  int8_t* Wq = (int8_t*)(ws + 0x200000 + (size_t)M_DIM * K_DIM);     // 16 MiB

  abssum_stage1<<<512, 256, 0, stream>>>(w, s1);
  abssum_stage2<<<16, 256, 0, stream>>>(s1, s2);
  gamma_stage3<<<1, 256, 0, stream>>>(s2, gamma_f);
  zero_counts<<<1, 64, 0, stream>>>(counts);
  wq_kernel<<<(N_DIM * K_DIM / 4 + 255) / 256, 256, 0, stream>>>(
      (const float4*)w, gamma_f, (int*)Wq, counts, buckets);
  lnq_kernel<<<M_DIM, 256, 0, stream>>>(x, gamma_f, Aq, scales);
  dim3 grid(N_DIM / 128, M_DIM / 128);
  gemm_i8_kernel<<<grid, 256, 0, stream>>>(Aq, Wq, scales, bias, counts, buckets, out);
}

// Round 8
// 293.272 us; speedup vs baseline: 3.6432x; 3.6432x over previous
//
#include <hip/hip_runtime.h>
#include <stdint.h>

typedef int v4i __attribute__((ext_vector_type(4)));

#define M_DIM 8192   // B*S = 2*4096
#define N_DIM 8192   // OUT
#define K_DIM 2048   // IN
#define RISKY_TAU 1e-4f
#define BUCKET_CAP 1024
#define SLOT 16384   // LDS buffer: A[128][64] 8KB + B[128][64] 8KB

// async global->LDS, 16B per lane (dest = wave-uniform base + lane*16)
#define ASYNC16(g, l) __builtin_amdgcn_global_load_lds(                        \
    (const __attribute__((address_space(1))) void*)(uintptr_t)(g),             \
    (__attribute__((address_space(3))) void*)(uint32_t)(uintptr_t)(l), 16, 0, 0)

// ---------------- 1) numpy-pairwise f32 sum of |w| ----------------
__global__ __launch_bounds__(256) void abssum_stage1(const float* __restrict__ w,
                                                     float* __restrict__ s1) {
  int b = blockIdx.x * 256 + threadIdx.x;  // 131072 leaf blocks of 128
  const float* p = w + (size_t)b * 128;
  float r[8];
#pragma unroll
  for (int j = 0; j < 8; j++) r[j] = fabsf(p[j]);
  for (int i = 8; i < 128; i += 8) {
#pragma unroll
    for (int j = 0; j < 8; j++) r[j] += fabsf(p[i + j]);
  }
  s1[b] = ((r[0] + r[1]) + (r[2] + r[3])) + ((r[4] + r[5]) + (r[6] + r[7]));
}

__global__ __launch_bounds__(256) void abssum_stage2(const float* __restrict__ s1,
                                                     float* __restrict__ s2) {
  int t = blockIdx.x * 256 + threadIdx.x;  // 4096 threads
  float v[32];
#pragma unroll
  for (int i = 0; i < 32; i++) v[i] = s1[t * 32 + i];
#pragma unroll
  for (int s = 1; s < 32; s *= 2) {
#pragma unroll
    for (int i = 0; i < 32; i += 2 * s) v[i] += v[i + s];
  }
  s2[t] = v[0];
}

__global__ __launch_bounds__(256) void gamma_stage3(const float* __restrict__ s2,
                                                    float* __restrict__ gp) {
  int t = threadIdx.x;  // 256 threads, one block
  float v[16];
#pragma unroll
  for (int i = 0; i < 16; i++) v[i] = s2[t * 16 + i];
#pragma unroll
  for (int s = 1; s < 16; s *= 2) {
#pragma unroll
    for (int i = 0; i < 16; i += 2 * s) v[i] += v[i + s];
  }
  __shared__ float sm[256];
  sm[t] = v[0];
  for (int s = 1; s < 256; s *= 2) {
    __syncthreads();
    if ((t & (2 * s - 1)) == 0) sm[t] += sm[t + s];
  }
  __syncthreads();
  if (t == 0) {
    float g = sm[0] * 0x1p-24f;  // /(8192*2048), exact pow2 scale
    gp[0] = fmaxf(g, 1e-5f);
  }
}

__global__ void zero_counts(int* __restrict__ counts) {
  counts[threadIdx.x] = 0;
}

// ---------------- 2) ternary weight quant + risky-midpoint detection ----------------
__global__ __launch_bounds__(256) void wq_kernel(const float4* __restrict__ w4,
                                                 const float* __restrict__ gp,
                                                 int* __restrict__ wq,
                                                 int* __restrict__ counts,
                                                 int* __restrict__ buckets) {
  int i = blockIdx.x * 256 + threadIdx.x;
  float g = gp[0];
  float4 v = w4[i];
  float e[4] = {v.x, v.y, v.z, v.w};
  int q[4];
#pragma unroll
  for (int c = 0; c < 4; c++) {
    q[c] = (int)rintf(fminf(fmaxf(e[c] / g, -1.0f), 1.0f));
    float t = fabsf(e[c]) / g;
    if (fabsf(t - 0.5f) < RISKY_TAU) {
      int flat = i * 4 + c;
      int n = flat >> 11;          // weight row (output col)
      int k = flat & 2047;
      int sgn_neg = (e[c] < 0.0f) ? 1 : 0;
      int sbit = (q[c] == 0) ? sgn_neg : (1 - sgn_neg);
      int b = n >> 7;
      int idx = atomicAdd(&counts[b], 1);
      if (idx < BUCKET_CAP)
        buckets[b * BUCKET_CAP + idx] = k | (n << 11) | (sbit << 24);
    }
  }
  wq[i] = (q[0] & 0xFF) | ((q[1] & 0xFF) << 8) | ((q[2] & 0xFF) << 16) | ((q[3] & 0xFF) << 24);
}

// ---------------- 3) fused LayerNorm + absmax int8 quant (one block per row) ----------------
__global__ __launch_bounds__(256) void lnq_kernel(const float* __restrict__ x,
                                                  const float* __restrict__ gp,
                                                  int8_t* __restrict__ xq,
                                                  float* __restrict__ scales) {
  const int row = blockIdx.x;
  const int t = threadIdx.x;
  const float4* xr = (const float4*)(x + (size_t)row * K_DIM);
  float4 a = xr[t];
  float4 b = xr[t + 256];
  double v[8] = {a.x, a.y, a.z, a.w, b.x, b.y, b.z, b.w};
  double s = 0.0, ss = 0.0;
#pragma unroll
  for (int i = 0; i < 8; i++) { s += v[i]; ss += v[i] * v[i]; }
  __shared__ double sm1[256], sm2[256];
  sm1[t] = s; sm2[t] = ss;
  __syncthreads();
  for (int off = 128; off > 0; off >>= 1) {
    if (t < off) { sm1[t] += sm1[t + off]; sm2[t] += sm2[t + off]; }
    __syncthreads();
  }
  double mu = sm1[0] * (1.0 / 2048.0);
  double var = sm2[0] * (1.0 / 2048.0) - mu * mu;  // biased variance
  double inv = 1.0 / sqrt(var + 1e-5);
  __syncthreads();
  double mx = 0.0;
#pragma unroll
  for (int i = 0; i < 8; i++) {
    v[i] = (v[i] - mu) * inv;
    double av = fabs(v[i]);
    if (av > mx) mx = av;
  }
  sm1[t] = mx;
  __syncthreads();
  for (int off = 128; off > 0; off >>= 1) {
    if (t < off) sm1[t] = fmax(sm1[t], sm1[t + off]);
    __syncthreads();
  }
  double eta = fmax(sm1[0], 1e-5);
  double r = 127.0 / eta;
  int q[8];
#pragma unroll
  for (int i = 0; i < 8; i++) {
    double qq = rint(v[i] * r);  // round-half-even, then clip
    qq = fmin(fmax(qq, -128.0), 127.0);
    q[i] = (int)qq;
  }
  int p0 = (q[0] & 0xFF) | ((q[1] & 0xFF) << 8) | ((q[2] & 0xFF) << 16) | ((q[3] & 0xFF) << 24);
  int p1 = (q[4] & 0xFF) | ((q[5] & 0xFF) << 8) | ((q[6] & 0xFF) << 16) | ((q[7] & 0xFF) << 24);
  int* orow = (int*)(xq + (size_t)row * K_DIM);
  orow[t] = p0;
  orow[t + 256] = p1;
  if (t == 0) scales[row] = (float)((double)gp[0] * eta * (1.0 / 127.0));
}

// ---------------- 4) int8 MFMA GEMM: 128x128 tile, 2-phase double-buffer ----------------
// Round-4 base (proven 150MB FETCH / 262MB WRITE traffic) + minimum-2-phase pipeline:
// stage tile t+1 into buf^1 BEFORE computing tile t; ONE __syncthreads per K-step.
// Depth-1 prefetch (4 loads/wave in flight, drained every iter) == round-4 footprint.
// Normal C stores (nontemporal was the round-7 traffic disaster). No forced occupancy.
__global__ __launch_bounds__(256) void gemm_i8_kernel(const int8_t* __restrict__ A,
                                                      const int8_t* __restrict__ B,
                                                      const float* __restrict__ scales,
                                                      const float* __restrict__ bias,
                                                      const int* __restrict__ counts,
                                                      const int* __restrict__ buckets,
                                                      float* __restrict__ C) {
  __shared__ alignas(16) int8_t lds[2 * SLOT];  // 32 KiB
  const int tid = threadIdx.x;
  const int wave = tid >> 6;
  const int lane = tid & 63;
  const int brow = blockIdx.y * 128;
  const int bcol = blockIdx.x * 128;

  // staging: 8 chunks of 1024B per matrix per tile; wave handles chunks {2w, 2w+1}.
  const int rA0 = (wave * 2 + 0) * 16 + (lane >> 2);
  const int rA1 = (wave * 2 + 1) * 16 + (lane >> 2);
  const int c16 = lane & 3;
  const int cA0 = ((c16 ^ ((rA0 >> 1) & 3)) << 4);
  const int cA1 = ((c16 ^ ((rA1 >> 1) & 3)) << 4);
  const int8_t* gA0 = A + (size_t)(brow + rA0) * K_DIM + cA0;
  const int8_t* gA1 = A + (size_t)(brow + rA1) * K_DIM + cA1;
  const int8_t* gB0 = B + (size_t)(bcol + rA0) * K_DIM + cA0;
  const int8_t* gB1 = B + (size_t)(bcol + rA1) * K_DIM + cA1;
  const int dA0 = (wave * 2 + 0) * 1024;          // buffer-relative LDS dests (wave-uniform)
  const int dA1 = (wave * 2 + 1) * 1024;
  const int dB0 = 8192 + (wave * 2 + 0) * 1024;
  const int dB1 = 8192 + (wave * 2 + 1) * 1024;

  // fragment read offsets (swizzled), buffer-relative
  const int wr = wave >> 1, wc = wave & 1;
  int aoff[4], boff[4];
#pragma unroll
  for (int i = 0; i < 4; i++) {
    int lr = wr * 64 + i * 16 + (lane & 15);
    aoff[i] = lr * 64 + ((((lane >> 4) ^ ((lr >> 1) & 3))) << 4);
    int lc = wc * 64 + i * 16 + (lane & 15);
    boff[i] = 8192 + lc * 64 + ((((lane >> 4) ^ ((lc >> 1) & 3))) << 4);
  }

  v4i acc[4][4];
  const v4i vzero = {0, 0, 0, 0};
#pragma unroll
  for (int i = 0; i < 4; i++)
#pragma unroll
    for (int j = 0; j < 4; j++) acc[i][j] = vzero;

  // prologue: stage tile 0 -> buf 0; drain
  ASYNC16(gA0, lds + dA0);
  ASYNC16(gA1, lds + dA1);
  ASYNC16(gB0, lds + dB0);
  ASYNC16(gB1, lds + dB1);
  __syncthreads();  // vmcnt(0): tile 0 landed

  int cur = 0;
  for (int t = 0; t < 32; ++t) {
    // issue next-tile staging first (hides under this tile's ds_read+MFMA)
    if (t < 31) {
      const int kt = (t + 1) * 64;
      const int sb = (cur ^ 1) * SLOT;
      ASYNC16(gA0 + kt, lds + sb + dA0);
      ASYNC16(gA1 + kt, lds + sb + dA1);
      ASYNC16(gB0 + kt, lds + sb + dB0);
      ASYNC16(gB1 + kt, lds + sb + dB1);
    }
    const int rb = cur * SLOT;
    v4i af[4], bf[4];
#pragma unroll
    for (int i = 0; i < 4; i++) af[i] = *(const v4i*)(lds + rb + aoff[i]);
#pragma unroll
    for (int j = 0; j < 4; j++) bf[j] = *(const v4i*)(lds + rb + boff[j]);
    __builtin_amdgcn_s_setprio(1);
#pragma unroll
    for (int i = 0; i < 4; i++)
#pragma unroll
      for (int j = 0; j < 4; j++)
        acc[i][j] = __builtin_amdgcn_mfma_i32_16x16x64_i8(af[i], bf[j], acc[i][j], 0, 0, 0);
    __builtin_amdgcn_s_setprio(0);
    __syncthreads();  // one drain per K-step: tile t+1 landed; ds_reads of buf done
    cur ^= 1;
  }

  // double accumulators (midpoint = odd integer), then apply risky corrections
#pragma unroll
  for (int i = 0; i < 4; i++)
#pragma unroll
    for (int j = 0; j < 4; j++) acc[i][j] = acc[i][j] + acc[i][j];

  const int crow0 = brow + wr * 64;
  const int ccol0 = bcol + wc * 64;

#define CORR(J)                                                                \
  {                                                                            \
    _Pragma("unroll") for (int i = 0; i < 4; i++) {                            \
      _Pragma("unroll") for (int r = 0; r < 4; r++) {                          \
        int grow = crow0 + i * 16 + ((lane >> 4) << 2) + r;                    \
        int xv = (int)A[(size_t)grow * K_DIM + k];                             \
        acc[i][J][r] += sv * xv;                                               \
      }                                                                        \
    }                                                                          \
  }

  {
    int bkt = bcol >> 7;
    int cnt = counts[bkt];
    if (cnt > BUCKET_CAP) cnt = BUCKET_CAP;
    const int* bk = buckets + bkt * BUCKET_CAP;
    for (int e = 0; e < cnt; ++e) {
      int word = bk[e];
      int k = word & 2047;
      int n = (word >> 11) & 8191;
      int sv = ((word >> 24) & 1) ? -1 : 1;
      int lc = n - bcol;  // in [0,128)
      if (((lc >> 6) & 1) == wc && (lc & 15) == (lane & 15)) {
        int j = (lc >> 4) & 3;
        switch (j) {
          case 0: CORR(0); break;
          case 1: CORR(1); break;
          case 2: CORR(2); break;
          case 3: CORR(3); break;
        }
      }
    }
  }
#undef CORR

  // epilogue: C[m][n] = (2*acc_corrected) * (scale_m/2) + bias[n]  (normal cached stores)
#pragma unroll
  for (int i = 0; i < 4; i++) {
#pragma unroll
    for (int r = 0; r < 4; r++) {
      int grow = crow0 + i * 16 + ((lane >> 4) << 2) + r;
      float sc = scales[grow] * 0.5f;
      float* crow = C + (size_t)grow * N_DIM;
#pragma unroll
      for (int j = 0; j < 4; j++) {
        int gcol = ccol0 + j * 16 + (lane & 15);
        crow[gcol] = (float)acc[i][j][r] * sc + bias[gcol];
      }
    }
  }
}

extern "C" void kernel_launch(void* const* d_in, const int* in_sizes, int n_in,
                              void* d_out, int out_size, void* d_ws, size_t ws_size,
                              hipStream_t stream) {
  const float* x = (const float*)d_in[0];
  const float* w = (const float*)d_in[1];
  const float* bias = (const float*)d_in[2];
  float* out = (float*)d_out;

  char* ws = (char*)d_ws;
  float* s1 = (float*)(ws);                          // 512 KiB
  float* s2 = (float*)(ws + 0x100000);               // 16 KiB
  float* gamma_f = (float*)(ws + 0x110000);          // 4 B
  float* scales = (float*)(ws + 0x120000);           // 32 KiB
  int* counts = (int*)(ws + 0x130000);               // 64 * 4 B
  int* buckets = (int*)(ws + 0x131000);              // 256 KiB
  int8_t* Aq = (int8_t*)(ws + 0x200000);                             // 16 MiB
  int8_t* Wq = (int8_t*)(ws + 0x200000 + (size_t)M_DIM * K_DIM);     // 16 MiB

  abssum_stage1<<<512, 256, 0, stream>>>(w, s1);
  abssum_stage2<<<16, 256, 0, stream>>>(s1, s2);
  gamma_stage3<<<1, 256, 0, stream>>>(s2, gamma_f);
  zero_counts<<<1, 64, 0, stream>>>(counts);
  wq_kernel<<<(N_DIM * K_DIM / 4 + 255) / 256, 256, 0, stream>>>(
      (const float4*)w, gamma_f, (int*)Wq, counts, buckets);
  lnq_kernel<<<M_DIM, 256, 0, stream>>>(x, gamma_f, Aq, scales);
  dim3 grid(N_DIM / 128, M_DIM / 128);
  gemm_i8_kernel<<<grid, 256, 0, stream>>>(Aq, Wq, scales, bias, counts, buckets, out);
}

// Round 9
// 267.525 us; speedup vs baseline: 3.9939x; 1.0962x over previous
//
#include <hip/hip_runtime.h>
#include <stdint.h>

typedef int v4i __attribute__((ext_vector_type(4)));

#define M_DIM 8192   // B*S = 2*4096
#define N_DIM 8192   // OUT
#define K_DIM 2048   // IN
#define RISKY_TAU 1e-4f
#define BUCKET_CAP 1024
#define SLOT 32768   // LDS buffer: A[128][128] 16KB + B[128][128] 16KB

// async global->LDS, 16B per lane (dest = wave-uniform base + lane*16)
#define ASYNC16(g, l) __builtin_amdgcn_global_load_lds(                        \
    (const __attribute__((address_space(1))) void*)(uintptr_t)(g),             \
    (__attribute__((address_space(3))) void*)(uint32_t)(uintptr_t)(l), 16, 0, 0)

// ---------------- 1) numpy-pairwise f32 sum of |w| ----------------
__global__ __launch_bounds__(256) void abssum_stage1(const float* __restrict__ w,
                                                     float* __restrict__ s1) {
  int b = blockIdx.x * 256 + threadIdx.x;  // 131072 leaf blocks of 128
  const float* p = w + (size_t)b * 128;
  float r[8];
#pragma unroll
  for (int j = 0; j < 8; j++) r[j] = fabsf(p[j]);
  for (int i = 8; i < 128; i += 8) {
#pragma unroll
    for (int j = 0; j < 8; j++) r[j] += fabsf(p[i + j]);
  }
  s1[b] = ((r[0] + r[1]) + (r[2] + r[3])) + ((r[4] + r[5]) + (r[6] + r[7]));
}

__global__ __launch_bounds__(256) void abssum_stage2(const float* __restrict__ s1,
                                                     float* __restrict__ s2) {
  int t = blockIdx.x * 256 + threadIdx.x;  // 4096 threads
  float v[32];
#pragma unroll
  for (int i = 0; i < 32; i++) v[i] = s1[t * 32 + i];
#pragma unroll
  for (int s = 1; s < 32; s *= 2) {
#pragma unroll
    for (int i = 0; i < 32; i += 2 * s) v[i] += v[i + s];
  }
  s2[t] = v[0];
}

__global__ __launch_bounds__(256) void gamma_stage3(const float* __restrict__ s2,
                                                    float* __restrict__ gp) {
  int t = threadIdx.x;  // 256 threads, one block
  float v[16];
#pragma unroll
  for (int i = 0; i < 16; i++) v[i] = s2[t * 16 + i];
#pragma unroll
  for (int s = 1; s < 16; s *= 2) {
#pragma unroll
    for (int i = 0; i < 16; i += 2 * s) v[i] += v[i + s];
  }
  __shared__ float sm[256];
  sm[t] = v[0];
  for (int s = 1; s < 256; s *= 2) {
    __syncthreads();
    if ((t & (2 * s - 1)) == 0) sm[t] += sm[t + s];
  }
  __syncthreads();
  if (t == 0) {
    float g = sm[0] * 0x1p-24f;  // /(8192*2048), exact pow2 scale
    gp[0] = fmaxf(g, 1e-5f);
  }
}

__global__ void zero_counts(int* __restrict__ counts) {
  counts[threadIdx.x] = 0;
}

// ---------------- 2) ternary weight quant + risky-midpoint detection ----------------
__global__ __launch_bounds__(256) void wq_kernel(const float4* __restrict__ w4,
                                                 const float* __restrict__ gp,
                                                 int* __restrict__ wq,
                                                 int* __restrict__ counts,
                                                 int* __restrict__ buckets) {
  int i = blockIdx.x * 256 + threadIdx.x;
  float g = gp[0];
  float4 v = w4[i];
  float e[4] = {v.x, v.y, v.z, v.w};
  int q[4];
#pragma unroll
  for (int c = 0; c < 4; c++) {
    q[c] = (int)rintf(fminf(fmaxf(e[c] / g, -1.0f), 1.0f));
    float t = fabsf(e[c]) / g;
    if (fabsf(t - 0.5f) < RISKY_TAU) {
      int flat = i * 4 + c;
      int n = flat >> 11;          // weight row (output col)
      int k = flat & 2047;
      int sgn_neg = (e[c] < 0.0f) ? 1 : 0;
      int sbit = (q[c] == 0) ? sgn_neg : (1 - sgn_neg);
      int b = n >> 7;
      int idx = atomicAdd(&counts[b], 1);
      if (idx < BUCKET_CAP)
        buckets[b * BUCKET_CAP + idx] = k | (n << 11) | (sbit << 24);
    }
  }
  wq[i] = (q[0] & 0xFF) | ((q[1] & 0xFF) << 8) | ((q[2] & 0xFF) << 16) | ((q[3] & 0xFF) << 24);
}

// ---------------- 3) fused LayerNorm + absmax int8 quant (one block per row) ----------------
__global__ __launch_bounds__(256) void lnq_kernel(const float* __restrict__ x,
                                                  const float* __restrict__ gp,
                                                  int8_t* __restrict__ xq,
                                                  float* __restrict__ scales) {
  const int row = blockIdx.x;
  const int t = threadIdx.x;
  const float4* xr = (const float4*)(x + (size_t)row * K_DIM);
  float4 a = xr[t];
  float4 b = xr[t + 256];
  double v[8] = {a.x, a.y, a.z, a.w, b.x, b.y, b.z, b.w};
  double s = 0.0, ss = 0.0;
#pragma unroll
  for (int i = 0; i < 8; i++) { s += v[i]; ss += v[i] * v[i]; }
  __shared__ double sm1[256], sm2[256];
  sm1[t] = s; sm2[t] = ss;
  __syncthreads();
  for (int off = 128; off > 0; off >>= 1) {
    if (t < off) { sm1[t] += sm1[t + off]; sm2[t] += sm2[t + off]; }
    __syncthreads();
  }
  double mu = sm1[0] * (1.0 / 2048.0);
  double var = sm2[0] * (1.0 / 2048.0) - mu * mu;  // biased variance
  double inv = 1.0 / sqrt(var + 1e-5);
  __syncthreads();
  double mx = 0.0;
#pragma unroll
  for (int i = 0; i < 8; i++) {
    v[i] = (v[i] - mu) * inv;
    double av = fabs(v[i]);
    if (av > mx) mx = av;
  }
  sm1[t] = mx;
  __syncthreads();
  for (int off = 128; off > 0; off >>= 1) {
    if (t < off) sm1[t] = fmax(sm1[t], sm1[t + off]);
    __syncthreads();
  }
  double eta = fmax(sm1[0], 1e-5);
  double r = 127.0 / eta;
  int q[8];
#pragma unroll
  for (int i = 0; i < 8; i++) {
    double qq = rint(v[i] * r);  // round-half-even, then clip
    qq = fmin(fmax(qq, -128.0), 127.0);
    q[i] = (int)qq;
  }
  int p0 = (q[0] & 0xFF) | ((q[1] & 0xFF) << 8) | ((q[2] & 0xFF) << 16) | ((q[3] & 0xFF) << 24);
  int p1 = (q[4] & 0xFF) | ((q[5] & 0xFF) << 8) | ((q[6] & 0xFF) << 16) | ((q[7] & 0xFF) << 24);
  int* orow = (int*)(xq + (size_t)row * K_DIM);
  orow[t] = p0;
  orow[t + 256] = p1;
  if (t == 0) scales[row] = (float)((double)gp[0] * eta * (1.0 / 127.0));
}

// ---------------- 4) int8 MFMA GEMM: 128x128 tile, BK=128, 2-phase double-buffer --------
// Round-8 structure with BK doubled: 16 K-steps, ONE __syncthreads per step; per-step
// compute (~590cyc MFMA + ~800cyc LDS) now exceeds L2/L3 load latency -> prefetch fully
// hidden. Staging: 8 chunks/wave of 1KB (8 rows x 128B), 8-slot XOR swizzle (<=2-way, free).
__global__ __launch_bounds__(256) void gemm_i8_kernel(const int8_t* __restrict__ A,
                                                      const int8_t* __restrict__ B,
                                                      const float* __restrict__ scales,
                                                      const float* __restrict__ bias,
                                                      const int* __restrict__ counts,
                                                      const int* __restrict__ buckets,
                                                      float* __restrict__ C) {
  __shared__ alignas(16) int8_t lds[2 * SLOT];  // 64 KiB
  const int tid = threadIdx.x;
  const int wave = tid >> 6;
  const int lane = tid & 63;
  const int brow = blockIdx.y * 128;
  const int bcol = blockIdx.x * 128;

  // staging: A tile 128 rows x 128B = 16 chunks of 1KB (8 rows each); wave w stages
  // chunks {4w..4w+3} of A and of B. lane -> row-in-chunk (lane>>3), slot (lane&7).
  const int ch_r = lane >> 3;
  const int sl = lane & 7;
  const int scol = ((sl ^ ch_r) << 4);  // swizzled source col within 128B row
  const int8_t* gA[4];
  const int8_t* gB[4];
  int dA[4], dB[4];
#pragma unroll
  for (int c = 0; c < 4; c++) {
    int r = 32 * wave + 8 * c + ch_r;  // tile row staged by this lane
    gA[c] = A + (size_t)(brow + r) * K_DIM + scol;
    gB[c] = B + (size_t)(bcol + r) * K_DIM + scol;
    dA[c] = (wave * 4 + c) * 1024;
    dB[c] = 16384 + (wave * 4 + c) * 1024;
  }

  // fragment read offsets (swizzled), buffer-relative, ks=0; ks=1 -> ^64
  const int wr = wave >> 1, wc = wave & 1;
  const int rslot = ((lane >> 4) ^ (lane & 7)) << 4;  // slot*16 for ks=0
  int aoff[4], boff[4];
#pragma unroll
  for (int i = 0; i < 4; i++) {
    int lr = wr * 64 + i * 16 + (lane & 15);
    aoff[i] = lr * 128 + rslot;
    int lc = wc * 64 + i * 16 + (lane & 15);
    boff[i] = 16384 + lc * 128 + rslot;
  }

  v4i acc[4][4];
  const v4i vzero = {0, 0, 0, 0};
#pragma unroll
  for (int i = 0; i < 4; i++)
#pragma unroll
    for (int j = 0; j < 4; j++) acc[i][j] = vzero;

  // prologue: stage tile 0 -> buf 0; drain
#pragma unroll
  for (int c = 0; c < 4; c++) {
    ASYNC16(gA[c], lds + dA[c]);
    ASYNC16(gB[c], lds + dB[c]);
  }
  __syncthreads();  // vmcnt(0): tile 0 landed

  int cur = 0;
  for (int t = 0; t < 16; ++t) {
    // issue next-tile staging first (hides under this tile's ds_read+MFMA)
    if (t < 15) {
      const int kt = (t + 1) * 128;
      const int sb = (cur ^ 1) * SLOT;
#pragma unroll
      for (int c = 0; c < 4; c++) {
        ASYNC16(gA[c] + kt, lds + sb + dA[c]);
        ASYNC16(gB[c] + kt, lds + sb + dB[c]);
      }
    }
    const int rb = cur * SLOT;
#pragma unroll
    for (int ks = 0; ks < 2; ks++) {
      const int kx = ks << 6;  // ^64 selects K-subtile 1
      v4i af[4], bf[4];
#pragma unroll
      for (int i = 0; i < 4; i++) af[i] = *(const v4i*)(lds + rb + (aoff[i] ^ kx));
#pragma unroll
      for (int j = 0; j < 4; j++) bf[j] = *(const v4i*)(lds + rb + (boff[j] ^ kx));
      __builtin_amdgcn_s_setprio(1);
#pragma unroll
      for (int i = 0; i < 4; i++)
#pragma unroll
        for (int j = 0; j < 4; j++)
          acc[i][j] = __builtin_amdgcn_mfma_i32_16x16x64_i8(af[i], bf[j], acc[i][j], 0, 0, 0);
      __builtin_amdgcn_s_setprio(0);
    }
    __syncthreads();  // one drain per K-step: tile t+1 landed; ds_reads of buf done
    cur ^= 1;
  }

  // double accumulators (midpoint = odd integer), then apply risky corrections
#pragma unroll
  for (int i = 0; i < 4; i++)
#pragma unroll
    for (int j = 0; j < 4; j++) acc[i][j] = acc[i][j] + acc[i][j];

  const int crow0 = brow + wr * 64;
  const int ccol0 = bcol + wc * 64;

#define CORR(J)                                                                \
  {                                                                            \
    _Pragma("unroll") for (int i = 0; i < 4; i++) {                            \
      _Pragma("unroll") for (int r = 0; r < 4; r++) {                          \
        int grow = crow0 + i * 16 + ((lane >> 4) << 2) + r;                    \
        int xv = (int)A[(size_t)grow * K_DIM + k];                             \
        acc[i][J][r] += sv * xv;                                               \
      }                                                                        \
    }                                                                          \
  }

  {
    int bkt = bcol >> 7;
    int cnt = counts[bkt];
    if (cnt > BUCKET_CAP) cnt = BUCKET_CAP;
    const int* bk = buckets + bkt * BUCKET_CAP;
    for (int e = 0; e < cnt; ++e) {
      int word = bk[e];
      int k = word & 2047;
      int n = (word >> 11) & 8191;
      int sv = ((word >> 24) & 1) ? -1 : 1;
      int lc = n - bcol;  // in [0,128)
      if (((lc >> 6) & 1) == wc && (lc & 15) == (lane & 15)) {
        int j = (lc >> 4) & 3;
        switch (j) {
          case 0: CORR(0); break;
          case 1: CORR(1); break;
          case 2: CORR(2); break;
          case 3: CORR(3); break;
        }
      }
    }
  }
#undef CORR

  // epilogue: C[m][n] = (2*acc_corrected) * (scale_m/2) + bias[n]  (normal cached stores)
#pragma unroll
  for (int i = 0; i < 4; i++) {
#pragma unroll
    for (int r = 0; r < 4; r++) {
      int grow = crow0 + i * 16 + ((lane >> 4) << 2) + r;
      float sc = scales[grow] * 0.5f;
      float* crow = C + (size_t)grow * N_DIM;
#pragma unroll
      for (int j = 0; j < 4; j++) {
        int gcol = ccol0 + j * 16 + (lane & 15);
        crow[gcol] = (float)acc[i][j][r] * sc + bias[gcol];
      }
    }
  }
}

extern "C" void kernel_launch(void* const* d_in, const int* in_sizes, int n_in,
                              void* d_out, int out_size, void* d_ws, size_t ws_size,
                              hipStream_t stream) {
  const float* x = (const float*)d_in[0];
  const float* w = (const float*)d_in[1];
  const float* bias = (const float*)d_in[2];
  float* out = (float*)d_out;

  char* ws = (char*)d_ws;
  float* s1 = (float*)(ws);                          // 512 KiB
  float* s2 = (float*)(ws + 0x100000);               // 16 KiB
  float* gamma_f = (float*)(ws + 0x110000);          // 4 B
  float* scales = (float*)(ws + 0x120000);           // 32 KiB
  int* counts = (int*)(ws + 0x130000);               // 64 * 4 B
  int* buckets = (int*)(ws + 0x131000);              // 256 KiB
  int8_t* Aq = (int8_t*)(ws + 0x200000);                             // 16 MiB
  int8_t* Wq = (int8_t*)(ws + 0x200000 + (size_t)M_DIM * K_DIM);     // 16 MiB

  abssum_stage1<<<512, 256, 0, stream>>>(w, s1);
  abssum_stage2<<<16, 256, 0, stream>>>(s1, s2);
  gamma_stage3<<<1, 256, 0, stream>>>(s2, gamma_f);
  zero_counts<<<1, 64, 0, stream>>>(counts);
  wq_kernel<<<(N_DIM * K_DIM / 4 + 255) / 256, 256, 0, stream>>>(
      (const float4*)w, gamma_f, (int*)Wq, counts, buckets);
  lnq_kernel<<<M_DIM, 256, 0, stream>>>(x, gamma_f, Aq, scales);
  dim3 grid(N_DIM / 128, M_DIM / 128);
  gemm_i8_kernel<<<grid, 256, 0, stream>>>(Aq, Wq, scales, bias, counts, buckets, out);
}